// Round 5
// baseline (200.460 us; speedup 1.0000x reference)
//
#include <hip/hip_runtime.h>
#include <hip/hip_bf16.h>
#include <math.h>

#define DIM 1024
#define NHEADS 16
#define HD 64
#define WIN 256
#define NB 16
#define NSEQ 4096
#define NACC 512
#define LCTX 769      // 1 + 512 + 256
#define MROWS 12304   // 16*769
#define MPAD2 12544   // 49*256
#define NKV 2048

typedef short bf16x8 __attribute__((ext_vector_type(8)));
typedef float f32x4 __attribute__((ext_vector_type(4)));

__device__ inline unsigned short f2b(float f) {
    union { float f; unsigned int u; } c; c.f = f;
    unsigned int u = c.u;
    u += 0x7FFFu + ((u >> 16) & 1u);
    return (unsigned short)(u >> 16);
}
__device__ inline float b2f(unsigned short h) {
    union { unsigned int u; float f; } c; c.u = ((unsigned int)h) << 16;
    return c.f;
}

// ---------------------------------------------------------------------------
// Kernel 1: build ctx rows + LN1 -> normed(bf16), new_acc, ctx0
//           AND (blocks >= MPAD2) convert in_proj_w -> bf16
// ---------------------------------------------------------------------------
__global__ __launch_bounds__(256) void build_ln_kernel(
    const float* __restrict__ x, const float* __restrict__ state,
    const float* __restrict__ acc_ctx, const int* __restrict__ fix_pt,
    const float* __restrict__ ln1_g, const float* __restrict__ ln1_b,
    const float* __restrict__ in_proj_w, unsigned short* __restrict__ Wb,
    unsigned short* __restrict__ normed, float* __restrict__ ctx0,
    float* __restrict__ newacc)
{
    int bid = blockIdx.x;
    int t = threadIdx.x;
    if (bid >= MPAD2) {
        // weight conversion: 3072 blocks x 256 thr x float4 = 3072*1024 floats
        int idx = (bid - MPAD2) * 256 + t;
        float4 v = ((const float4*)in_proj_w)[idx];
        ushort4 o;
        o.x = f2b(v.x); o.y = f2b(v.y); o.z = f2b(v.z); o.w = f2b(v.w);
        ((ushort4*)Wb)[idx] = o;
        return;
    }
    if (bid >= MROWS) {
        ushort4 z = make_ushort4(0, 0, 0, 0);
        ((ushort4*)(normed + (size_t)bid * DIM))[t] = z;
        return;
    }
    int b = bid / LCTX;
    int r = bid - b * LCTX;
    const float* src;
    if (r == 0) {
        src = state + (size_t)b * DIM;
    } else if (r <= NACC) {
        src = acc_ctx + ((size_t)b * NACC + (r - 1)) * DIM;
    } else {
        int fp = fix_pt[b];
        int start = fp - WIN / 2;
        if (start < 0) start = 0;
        if (start > NSEQ - WIN) start = NSEQ - WIN;
        src = x + ((size_t)b * NSEQ + start + (r - 1 - NACC)) * DIM;
    }
    float4 v = ((const float4*)src)[t];
    float s = v.x + v.y + v.z + v.w;
    float ss = v.x * v.x + v.y * v.y + v.z * v.z + v.w * v.w;
#pragma unroll
    for (int o = 32; o > 0; o >>= 1) { s += __shfl_down(s, o); ss += __shfl_down(ss, o); }
    __shared__ float rs[4], rss[4];
    int wid = t >> 6, lane = t & 63;
    if (lane == 0) { rs[wid] = s; rss[wid] = ss; }
    __syncthreads();
    float sum = rs[0] + rs[1] + rs[2] + rs[3];
    float sq  = rss[0] + rss[1] + rss[2] + rss[3];
    float mean = sum * (1.0f / DIM);
    float var = sq * (1.0f / DIM) - mean * mean;
    float rstd = rsqrtf(var + 1e-5f);
    float4 g  = ((const float4*)ln1_g)[t];
    float4 be = ((const float4*)ln1_b)[t];
    ushort4 nb;
    nb.x = f2b((v.x - mean) * rstd * g.x + be.x);
    nb.y = f2b((v.y - mean) * rstd * g.y + be.y);
    nb.z = f2b((v.z - mean) * rstd * g.z + be.z);
    nb.w = f2b((v.w - mean) * rstd * g.w + be.w);
    ((ushort4*)(normed + (size_t)bid * DIM))[t] = nb;
    if (r == 0) {
        ((float4*)(ctx0 + (size_t)b * DIM))[t] = v;
    } else {
        ((float4*)(newacc + ((size_t)b * (LCTX - 1) + (r - 1)) * DIM))[t] = v;
    }
}

// ---------------------------------------------------------------------------
// Kernel 2: KV GEMM, 256x256 tile, BK=64, 8 waves, 8-phase schedule
// 1D grid 392, XCD-partitioned: nt = bid&7 (one nt per XCD), mt = bid>>3
// ---------------------------------------------------------------------------
__device__ inline void stage_half(const unsigned short* __restrict__ g,
                                  unsigned short* l, int t)
{
    {
        int r = t >> 3, c8 = (t & 7) ^ (r & 7);
        __builtin_amdgcn_global_load_lds(
            (const __attribute__((address_space(1))) void*)(g + (size_t)r * 1024 + c8 * 8),
            (__attribute__((address_space(3))) void*)(l + (size_t)t * 8), 16, 0, 0);
    }
    {
        int t2 = t + 512;
        int r = t2 >> 3, c8 = (t2 & 7) ^ (r & 7);
        __builtin_amdgcn_global_load_lds(
            (const __attribute__((address_space(1))) void*)(g + (size_t)r * 1024 + c8 * 8),
            (__attribute__((address_space(3))) void*)(l + (size_t)t2 * 8), 16, 0, 0);
    }
}

__device__ inline bf16x8 ldsw(const unsigned short* h, int r, int c8)
{
    int slot = r * 8 + (c8 ^ (r & 7));
    return *(const bf16x8*)(h + slot * 8);
}

__global__ __launch_bounds__(512, 2) void kv_gemm8_kernel(
    const unsigned short* __restrict__ A,
    const unsigned short* __restrict__ Bw,
    const float* __restrict__ bias,
    unsigned short* __restrict__ C)
{
    __shared__ unsigned short sh[2][2][2][128 * 64];
    const int mt = blockIdx.x >> 3, nt = blockIdx.x & 7;
    const int t = threadIdx.x;
    const int wid = t >> 6, lane = t & 63;
    const int wm = wid >> 2, wn = wid & 3;
    const int l15 = lane & 15, l16 = lane >> 4;
    const int rB = (wn & 1) * 64;
    const unsigned short* Abase = A + (size_t)mt * 256 * 1024;
    const unsigned short* Bbase = Bw + (size_t)nt * 256 * 1024;

    f32x4 acc[8][4] = {};
    bf16x8 a[4][2], b[4][2];

    stage_half(Abase,                   &sh[0][0][0][0], t);
    stage_half(Abase + 128 * 1024,      &sh[0][0][1][0], t);
    stage_half(Bbase,                   &sh[0][1][0][0], t);
    stage_half(Bbase + 128 * 1024,      &sh[0][1][1][0], t);
    stage_half(Bbase + 64,              &sh[1][1][0][0], t);
    stage_half(Bbase + 128 * 1024 + 64, &sh[1][1][1][0], t);
    asm volatile("s_waitcnt vmcnt(4)" ::: "memory");
    __builtin_amdgcn_s_barrier();

    auto ktile = [&](int T, bool stA, bool stB, bool steady) {
        const int d = T & 1;
        const unsigned short* AH = &sh[d][0][wm][0];
        const unsigned short* BH = &sh[d][1][wn >> 1][0];
        const int kA = (T + 1) * 64;
        const int kB = (T + 2) * 64;

#pragma unroll
        for (int i = 0; i < 4; ++i) {
            a[i][0] = ldsw(AH, i * 16 + l15, l16);
            a[i][1] = ldsw(AH, i * 16 + l15, 4 + l16);
        }
#pragma unroll
        for (int j = 0; j < 2; ++j) {
            b[j][0] = ldsw(BH, rB + j * 16 + l15, l16);
            b[j][1] = ldsw(BH, rB + j * 16 + l15, 4 + l16);
        }
        if (stA) stage_half(Abase + kA, &sh[d ^ 1][0][0][0], t);
        __builtin_amdgcn_sched_barrier(0);
        __builtin_amdgcn_s_barrier();
        asm volatile("s_waitcnt lgkmcnt(0)" ::: "memory");
        __builtin_amdgcn_sched_barrier(0);
        __builtin_amdgcn_s_setprio(1);
#pragma unroll
        for (int i = 0; i < 4; ++i)
#pragma unroll
            for (int j = 0; j < 2; ++j) {
                acc[i][j] = __builtin_amdgcn_mfma_f32_16x16x32_bf16(a[i][0], b[j][0], acc[i][j], 0, 0, 0);
                acc[i][j] = __builtin_amdgcn_mfma_f32_16x16x32_bf16(a[i][1], b[j][1], acc[i][j], 0, 0, 0);
            }
        __builtin_amdgcn_s_setprio(0);
        __builtin_amdgcn_sched_barrier(0);
        __builtin_amdgcn_s_barrier();

#pragma unroll
        for (int j = 2; j < 4; ++j) {
            b[j][0] = ldsw(BH, rB + j * 16 + l15, l16);
            b[j][1] = ldsw(BH, rB + j * 16 + l15, 4 + l16);
        }
        if (stA) stage_half(Abase + 128 * 1024 + kA, &sh[d ^ 1][0][1][0], t);
        __builtin_amdgcn_sched_barrier(0);
        __builtin_amdgcn_s_barrier();
        asm volatile("s_waitcnt lgkmcnt(0)" ::: "memory");
        __builtin_amdgcn_sched_barrier(0);
        __builtin_amdgcn_s_setprio(1);
#pragma unroll
        for (int i = 0; i < 4; ++i)
#pragma unroll
            for (int j = 2; j < 4; ++j) {
                acc[i][j] = __builtin_amdgcn_mfma_f32_16x16x32_bf16(a[i][0], b[j][0], acc[i][j], 0, 0, 0);
                acc[i][j] = __builtin_amdgcn_mfma_f32_16x16x32_bf16(a[i][1], b[j][1], acc[i][j], 0, 0, 0);
            }
        __builtin_amdgcn_s_setprio(0);
        __builtin_amdgcn_sched_barrier(0);
        __builtin_amdgcn_s_barrier();

#pragma unroll
        for (int i = 0; i < 4; ++i) {
            a[i][0] = ldsw(AH, 64 + i * 16 + l15, l16);
            a[i][1] = ldsw(AH, 64 + i * 16 + l15, 4 + l16);
        }
        if (stB) stage_half(Bbase + kB, &sh[d][1][0][0], t);
        __builtin_amdgcn_sched_barrier(0);
        __builtin_amdgcn_s_barrier();
        asm volatile("s_waitcnt lgkmcnt(0)" ::: "memory");
        __builtin_amdgcn_sched_barrier(0);
        __builtin_amdgcn_s_setprio(1);
#pragma unroll
        for (int i = 0; i < 4; ++i)
#pragma unroll
            for (int j = 0; j < 2; ++j) {
                acc[4 + i][j] = __builtin_amdgcn_mfma_f32_16x16x32_bf16(a[i][0], b[j][0], acc[4 + i][j], 0, 0, 0);
                acc[4 + i][j] = __builtin_amdgcn_mfma_f32_16x16x32_bf16(a[i][1], b[j][1], acc[4 + i][j], 0, 0, 0);
            }
        __builtin_amdgcn_s_setprio(0);
        __builtin_amdgcn_sched_barrier(0);
        __builtin_amdgcn_s_barrier();

        if (stB) stage_half(Bbase + 128 * 1024 + kB, &sh[d][1][1][0], t);
        __builtin_amdgcn_sched_barrier(0);
        __builtin_amdgcn_s_barrier();
        asm volatile("s_waitcnt lgkmcnt(0)" ::: "memory");
        __builtin_amdgcn_sched_barrier(0);
        __builtin_amdgcn_s_setprio(1);
#pragma unroll
        for (int i = 0; i < 4; ++i)
#pragma unroll
            for (int j = 2; j < 4; ++j) {
                acc[4 + i][j] = __builtin_amdgcn_mfma_f32_16x16x32_bf16(a[i][0], b[j][0], acc[4 + i][j], 0, 0, 0);
                acc[4 + i][j] = __builtin_amdgcn_mfma_f32_16x16x32_bf16(a[i][1], b[j][1], acc[4 + i][j], 0, 0, 0);
            }
        __builtin_amdgcn_s_setprio(0);
        if (steady) {
            asm volatile("s_waitcnt vmcnt(4)" ::: "memory");
        } else {
            asm volatile("s_waitcnt vmcnt(0)" ::: "memory");
        }
        __builtin_amdgcn_sched_barrier(0);
        __builtin_amdgcn_s_barrier();
    };

    for (int T = 0; T < 14; ++T) ktile(T, true, true, true);
    ktile(14, true, false, false);
    ktile(15, false, false, false);

#pragma unroll
    for (int i = 0; i < 8; ++i) {
        int gmb = mt * 256 + wm * 128 + i * 16 + l16 * 4;
#pragma unroll
        for (int j = 0; j < 4; ++j) {
            int gn = nt * 256 + wn * 64 + j * 16 + l15;
            float bs = bias[gn];
#pragma unroll
            for (int r = 0; r < 4; ++r) {
                int gm = gmb + r;
                if (gm < MROWS) C[(size_t)gm * NKV + gn] = f2b(acc[i][j][r] + bs);
            }
        }
    }
}

// ---------------------------------------------------------------------------
// Kernel 3: attention decode with fused q-projection, one block per (b,h)
// ---------------------------------------------------------------------------
__global__ __launch_bounds__(512) void attn_kernel(
    const unsigned short* __restrict__ normed,
    const unsigned short* __restrict__ Wq, const float* __restrict__ bq,
    const unsigned short* __restrict__ kv, float* __restrict__ o_all)
{
    int b = blockIdx.x >> 4, h = blockIdx.x & 15;
    int t = threadIdx.x;
    int wave = t >> 6, lane = t & 63;
    __shared__ float qs[64];
    __shared__ float sc[LCTX];
    __shared__ float red1[8], red2[8];
    __shared__ float po[8][64];

    {
        const unsigned short* nr = normed + (size_t)(b * LCTX) * DIM;
        bf16x8 n0 = *(const bf16x8*)(nr + lane * 16);
        bf16x8 n1 = *(const bf16x8*)(nr + lane * 16 + 8);
#pragma unroll
        for (int jj = 0; jj < 8; ++jj) {
            int d = wave * 8 + jj;
            const unsigned short* wr = Wq + (size_t)(h * 64 + d) * DIM;
            bf16x8 w0 = *(const bf16x8*)(wr + lane * 16);
            bf16x8 w1 = *(const bf16x8*)(wr + lane * 16 + 8);
            float s = 0.f;
#pragma unroll
            for (int u = 0; u < 8; ++u)
                s += b2f((unsigned short)n0[u]) * b2f((unsigned short)w0[u]);
#pragma unroll
            for (int u = 0; u < 8; ++u)
                s += b2f((unsigned short)n1[u]) * b2f((unsigned short)w1[u]);
#pragma unroll
            for (int o = 32; o > 0; o >>= 1) s += __shfl_down(s, o);
            if (lane == 0) qs[d] = s + bq[h * 64 + d];
        }
    }
    __syncthreads();

    float lmax = -1e30f;
    for (int l = t; l < LCTX; l += 512) {
        const unsigned short* kr = kv + ((size_t)(b * LCTX + l)) * NKV + h * 64;
        const uint4* k4 = (const uint4*)kr;
        float s = 0.f;
#pragma unroll
        for (int c = 0; c < 8; ++c) {
            uint4 u = k4[c];
            s += qs[c * 8 + 0] * b2f((unsigned short)(u.x & 0xffffu));
            s += qs[c * 8 + 1] * b2f((unsigned short)(u.x >> 16));
            s += qs[c * 8 + 2] * b2f((unsigned short)(u.y & 0xffffu));
            s += qs[c * 8 + 3] * b2f((unsigned short)(u.y >> 16));
            s += qs[c * 8 + 4] * b2f((unsigned short)(u.z & 0xffffu));
            s += qs[c * 8 + 5] * b2f((unsigned short)(u.z >> 16));
            s += qs[c * 8 + 6] * b2f((unsigned short)(u.w & 0xffffu));
            s += qs[c * 8 + 7] * b2f((unsigned short)(u.w >> 16));
        }
        s *= 0.125f;
        sc[l] = s;
        lmax = fmaxf(lmax, s);
    }
#pragma unroll
    for (int o = 32; o > 0; o >>= 1) lmax = fmaxf(lmax, __shfl_down(lmax, o));
    if (lane == 0) red1[wave] = lmax;
    __syncthreads();
    float m = red1[0];
#pragma unroll
    for (int w8 = 1; w8 < 8; ++w8) m = fmaxf(m, red1[w8]);

    float lsum = 0.f;
    for (int l = t; l < LCTX; l += 512) {
        float p = __expf(sc[l] - m);
        sc[l] = p;
        lsum += p;
    }
#pragma unroll
    for (int o = 32; o > 0; o >>= 1) lsum += __shfl_down(lsum, o);
    if (lane == 0) red2[wave] = lsum;
    __syncthreads();
    float S = 0.f;
#pragma unroll
    for (int w8 = 0; w8 < 8; ++w8) S += red2[w8];

    int rg = lane >> 3;
    int dc = (lane & 7) * 8;
    float acc[8] = {};
    for (int it = 0; it < 13; ++it) {
        int row = it * 64 + wave * 8 + rg;
        if (row < LCTX) {
            const unsigned short* vr =
                kv + ((size_t)(b * LCTX + row)) * NKV + 1024 + h * 64 + dc;
            bf16x8 v = *(const bf16x8*)vr;
            float p = sc[row];
#pragma unroll
            for (int u = 0; u < 8; ++u) acc[u] += p * b2f((unsigned short)v[u]);
        }
    }
#pragma unroll
    for (int u = 0; u < 8; ++u) {
        acc[u] += __shfl_xor(acc[u], 8);
        acc[u] += __shfl_xor(acc[u], 16);
        acc[u] += __shfl_xor(acc[u], 32);
    }
    if (rg == 0) {
#pragma unroll
        for (int u = 0; u < 8; ++u) po[wave][dc + u] = acc[u];
    }
    __syncthreads();
    if (t < 64) {
        float o = 0.f;
#pragma unroll
        for (int w8 = 0; w8 < 8; ++w8) o += po[w8][t];
        o_all[b * 1024 + h * 64 + t] = o / S;
    }
}

// ---------------------------------------------------------------------------
// Kernel 4: fused out_proj + residual + LN2 + outp init; one block per b
// ---------------------------------------------------------------------------
__global__ __launch_bounds__(1024) void opln2_kernel(
    const float* __restrict__ o_all, const float* __restrict__ out_w,
    const float* __restrict__ out_b, const float* __restrict__ ctx0,
    const float* __restrict__ g, const float* __restrict__ be,
    const float* __restrict__ b2, float* __restrict__ ln2o,
    float* __restrict__ outp)
{
    int b = blockIdx.x, t = threadIdx.x;
    int wave = t >> 6, lane = t & 63;
    __shared__ float orow[1024];
    __shared__ float dots[1024];
    __shared__ float rs[16], rss[16];

    orow[t] = o_all[(size_t)b * 1024 + t];
    __syncthreads();

    // wave handles 64 consecutive outputs
    for (int jj = 0; jj < 64; ++jj) {
        int i = wave * 64 + jj;
        const float* wrow = out_w + (size_t)i * 1024;
        float s = 0.f;
#pragma unroll
        for (int kk = 0; kk < 16; ++kk) {
            int k = kk * 64 + lane;
            s += orow[k] * wrow[k];
        }
#pragma unroll
        for (int o = 32; o > 0; o >>= 1) s += __shfl_down(s, o);
        if (lane == 0) dots[i] = s;
    }
    __syncthreads();

    float v = ctx0[(size_t)b * 1024 + t] + dots[t] + out_b[t];
    float s = v, ss = v * v;
#pragma unroll
    for (int o = 32; o > 0; o >>= 1) { s += __shfl_down(s, o); ss += __shfl_down(ss, o); }
    if (lane == 0) { rs[wave] = s; rss[wave] = ss; }
    __syncthreads();
    float sum = 0.f, sq = 0.f;
#pragma unroll
    for (int w8 = 0; w8 < 16; ++w8) { sum += rs[w8]; sq += rss[w8]; }
    float mean = sum * (1.0f / DIM);
    float var = sq * (1.0f / DIM) - mean * mean;
    float rstd = rsqrtf(var + 1e-5f);
    ln2o[(size_t)b * 1024 + t] = (v - mean) * rstd * g[t] + be[t];
    outp[(size_t)b * 1024 + t] = v + b2[t];
}

// ---------------------------------------------------------------------------
// Kernel 5: mlp1 partials
// ---------------------------------------------------------------------------
__global__ __launch_bounds__(256) void mlp1p_kernel(
    const float* __restrict__ ln2v, const float* __restrict__ w1,
    float* __restrict__ part)
{
    __shared__ float l2s[16][256];
    __shared__ float red[4][64][16];
    int jc = blockIdx.x, kq = blockIdx.y;
    int t = threadIdx.x;
#pragma unroll
    for (int b = 0; b < 16; ++b)
        l2s[b][t] = ln2v[(size_t)b * 1024 + kq * 256 + t];
    __syncthreads();
    int jl = t & 63, ks = t >> 6;
    int j = jc * 64 + jl;
    float acc[16] = {};
    for (int kk = 0; kk < 64; ++kk) {
        int kl = ks * 64 + kk;
        float wv = w1[(size_t)(kq * 256 + kl) * 4096 + j];
#pragma unroll
        for (int b = 0; b < 16; ++b) acc[b] += l2s[b][kl] * wv;
    }
#pragma unroll
    for (int b = 0; b < 16; ++b) red[ks][jl][b] = acc[b];
    __syncthreads();
    int jl2 = t & 63, bq = t >> 6;
#pragma unroll
    for (int bb = 0; bb < 4; ++bb) {
        int b = bq * 4 + bb;
        float s = red[0][jl2][b] + red[1][jl2][b] + red[2][jl2][b] + red[3][jl2][b];
        part[((size_t)kq * 16 + b) * 4096 + jc * 64 + jl2] = s;
    }
}

// ---------------------------------------------------------------------------
// Kernel 6: mlp2 with in-LDS reduce+gelu of mlp1 partials, atomicAdd to outp
// ---------------------------------------------------------------------------
__global__ __launch_bounds__(256) void mlp2a_kernel(
    const float* __restrict__ part, const float* __restrict__ b1,
    const float* __restrict__ w2, float* __restrict__ outp)
{
    __shared__ float hseg[16][256];
    __shared__ float red[4][64][16];
    int ic = blockIdx.x, kq = blockIdx.y;
    int t = threadIdx.x;
    {
        int j = kq * 256 + t;
        float bb1 = b1[j];
#pragma unroll
        for (int b = 0; b < 16; ++b) {
            float s = part[((size_t)0 * 16 + b) * 4096 + j]
                    + part[((size_t)1 * 16 + b) * 4096 + j]
                    + part[((size_t)2 * 16 + b) * 4096 + j]
                    + part[((size_t)3 * 16 + b) * 4096 + j];
            s += bb1;
            hseg[b][t] = 0.5f * s * (1.0f + erff(s * 0.70710678118f));
        }
    }
    __syncthreads();
    int il = t & 63, ks = t >> 6;
    int i = ic * 64 + il;
    float acc[16] = {};
    for (int kk = 0; kk < 64; ++kk) {
        int kl = ks * 64 + kk;
        float wv = w2[(size_t)(kq * 256 + kl) * 1024 + i];
#pragma unroll
        for (int b = 0; b < 16; ++b) acc[b] += hseg[b][kl] * wv;
    }
#pragma unroll
    for (int b = 0; b < 16; ++b) red[ks][il][b] = acc[b];
    __syncthreads();
    int il2 = t & 63, bq = t >> 6;
#pragma unroll
    for (int bb = 0; bb < 4; ++bb) {
        int b = bq * 4 + bb;
        float s = red[0][il2][b] + red[1][il2][b] + red[2][il2][b] + red[3][il2][b];
        atomicAdd(&outp[(size_t)b * 1024 + ic * 64 + il2], s);
    }
}

// ---------------------------------------------------------------------------
extern "C" void kernel_launch(void* const* d_in, const int* in_sizes, int n_in,
                              void* d_out, int out_size, void* d_ws, size_t ws_size,
                              hipStream_t stream)
{
    const float* x        = (const float*)d_in[0];
    const float* state    = (const float*)d_in[1];
    const float* acc_ctx  = (const float*)d_in[2];
    const int*   fix_pt   = (const int*)d_in[3];
    const float* in_proj_w = (const float*)d_in[4];
    const float* in_proj_b = (const float*)d_in[5];
    const float* out_w    = (const float*)d_in[6];
    const float* out_b    = (const float*)d_in[7];
    const float* ln1_g    = (const float*)d_in[8];
    const float* ln1_b    = (const float*)d_in[9];
    const float* ln2_g    = (const float*)d_in[10];
    const float* ln2_b    = (const float*)d_in[11];
    const float* w1       = (const float*)d_in[12];
    const float* b1       = (const float*)d_in[13];
    const float* w2       = (const float*)d_in[14];
    const float* b2       = (const float*)d_in[15];
    float* outp = (float*)d_out;

    char* ws = (char*)d_ws;
    unsigned short* normed = (unsigned short*)ws; ws += (size_t)MPAD2 * DIM * 2;
    unsigned short* Wb     = (unsigned short*)ws; ws += (size_t)3072 * DIM * 2;
    unsigned short* kvb    = (unsigned short*)ws; ws += (size_t)MROWS * NKV * 2;
    float* ctx0    = (float*)ws; ws += (size_t)NB * DIM * 4;
    float* o_all   = (float*)ws; ws += (size_t)NB * DIM * 4;
    float* ln2v    = (float*)ws; ws += (size_t)NB * DIM * 4;
    float* part    = (float*)ws; ws += (size_t)4 * 16 * 4096 * 4;

    float* newacc = outp + (size_t)NB * DIM;

    hipLaunchKernelGGL(build_ln_kernel, dim3(MPAD2 + 3072), dim3(256), 0, stream,
                       x, state, acc_ctx, fix_pt, ln1_g, ln1_b,
                       in_proj_w, Wb, normed, ctx0, newacc);
    hipLaunchKernelGGL(kv_gemm8_kernel, dim3(392), dim3(512), 0, stream,
                       normed, Wb + (size_t)1024 * DIM, in_proj_b + 1024, kvb);
    hipLaunchKernelGGL(attn_kernel, dim3(256), dim3(512), 0, stream,
                       normed, Wb, in_proj_b, kvb, o_all);
    hipLaunchKernelGGL(opln2_kernel, dim3(16), dim3(1024), 0, stream,
                       o_all, out_w, out_b, ctx0, ln2_g, ln2_b, b2, ln2v, outp);
    hipLaunchKernelGGL(mlp1p_kernel, dim3(64, 4), dim3(256), 0, stream,
                       ln2v, w1, part);
    hipLaunchKernelGGL(mlp2a_kernel, dim3(16, 16), dim3(256), 0, stream,
                       part, b1, w2, outp);
}

// Round 6
// 165.047 us; speedup vs baseline: 1.2146x; 1.2146x over previous
//
#include <hip/hip_runtime.h>
#include <hip/hip_bf16.h>
#include <math.h>

#define DIM 1024
#define NHEADS 16
#define HD 64
#define WIN 256
#define NB 16
#define NSEQ 4096
#define NACC 512
#define LCTX 769      // 1 + 512 + 256
#define MROWS 12304   // 16*769
#define MPAD2 12544   // 49*256
#define NKV 2048

typedef short bf16x8 __attribute__((ext_vector_type(8)));
typedef float f32x4 __attribute__((ext_vector_type(4)));

__device__ inline unsigned short f2b(float f) {
    union { float f; unsigned int u; } c; c.f = f;
    unsigned int u = c.u;
    u += 0x7FFFu + ((u >> 16) & 1u);
    return (unsigned short)(u >> 16);
}
__device__ inline float b2f(unsigned short h) {
    union { unsigned int u; float f; } c; c.u = ((unsigned int)h) << 16;
    return c.f;
}

// ---------------------------------------------------------------------------
// Kernel 1: build ctx rows + LN1 -> normed(bf16), new_acc, ctx0
//           AND (blocks >= MPAD2) convert in_proj_w -> bf16
// ---------------------------------------------------------------------------
__global__ __launch_bounds__(256) void build_ln_kernel(
    const float* __restrict__ x, const float* __restrict__ state,
    const float* __restrict__ acc_ctx, const int* __restrict__ fix_pt,
    const float* __restrict__ ln1_g, const float* __restrict__ ln1_b,
    const float* __restrict__ in_proj_w, unsigned short* __restrict__ Wb,
    unsigned short* __restrict__ normed, float* __restrict__ ctx0,
    float* __restrict__ newacc)
{
    int bid = blockIdx.x;
    int t = threadIdx.x;
    if (bid >= MPAD2) {
        int idx = (bid - MPAD2) * 256 + t;
        float4 v = ((const float4*)in_proj_w)[idx];
        ushort4 o;
        o.x = f2b(v.x); o.y = f2b(v.y); o.z = f2b(v.z); o.w = f2b(v.w);
        ((ushort4*)Wb)[idx] = o;
        return;
    }
    if (bid >= MROWS) {
        ushort4 z = make_ushort4(0, 0, 0, 0);
        ((ushort4*)(normed + (size_t)bid * DIM))[t] = z;
        return;
    }
    int b = bid / LCTX;
    int r = bid - b * LCTX;
    const float* src;
    if (r == 0) {
        src = state + (size_t)b * DIM;
    } else if (r <= NACC) {
        src = acc_ctx + ((size_t)b * NACC + (r - 1)) * DIM;
    } else {
        int fp = fix_pt[b];
        int start = fp - WIN / 2;
        if (start < 0) start = 0;
        if (start > NSEQ - WIN) start = NSEQ - WIN;
        src = x + ((size_t)b * NSEQ + start + (r - 1 - NACC)) * DIM;
    }
    float4 v = ((const float4*)src)[t];
    float s = v.x + v.y + v.z + v.w;
    float ss = v.x * v.x + v.y * v.y + v.z * v.z + v.w * v.w;
#pragma unroll
    for (int o = 32; o > 0; o >>= 1) { s += __shfl_down(s, o); ss += __shfl_down(ss, o); }
    __shared__ float rs[4], rss[4];
    int wid = t >> 6, lane = t & 63;
    if (lane == 0) { rs[wid] = s; rss[wid] = ss; }
    __syncthreads();
    float sum = rs[0] + rs[1] + rs[2] + rs[3];
    float sq  = rss[0] + rss[1] + rss[2] + rss[3];
    float mean = sum * (1.0f / DIM);
    float var = sq * (1.0f / DIM) - mean * mean;
    float rstd = rsqrtf(var + 1e-5f);
    float4 g  = ((const float4*)ln1_g)[t];
    float4 be = ((const float4*)ln1_b)[t];
    ushort4 nb;
    nb.x = f2b((v.x - mean) * rstd * g.x + be.x);
    nb.y = f2b((v.y - mean) * rstd * g.y + be.y);
    nb.z = f2b((v.z - mean) * rstd * g.z + be.z);
    nb.w = f2b((v.w - mean) * rstd * g.w + be.w);
    ((ushort4*)(normed + (size_t)bid * DIM))[t] = nb;
    if (r == 0) {
        ((float4*)(ctx0 + (size_t)b * DIM))[t] = v;
    } else {
        ((float4*)(newacc + ((size_t)b * (LCTX - 1) + (r - 1)) * DIM))[t] = v;
    }
}

// ---------------------------------------------------------------------------
// Kernel 2: KV GEMM, 256x256 tile, BK=64, 8 waves, 8-phase schedule
// 1D grid 392, XCD-partitioned: nt = bid&7, mt = bid>>3
// ---------------------------------------------------------------------------
__device__ inline void stage_half(const unsigned short* __restrict__ g,
                                  unsigned short* l, int t)
{
    {
        int r = t >> 3, c8 = (t & 7) ^ (r & 7);
        __builtin_amdgcn_global_load_lds(
            (const __attribute__((address_space(1))) void*)(g + (size_t)r * 1024 + c8 * 8),
            (__attribute__((address_space(3))) void*)(l + (size_t)t * 8), 16, 0, 0);
    }
    {
        int t2 = t + 512;
        int r = t2 >> 3, c8 = (t2 & 7) ^ (r & 7);
        __builtin_amdgcn_global_load_lds(
            (const __attribute__((address_space(1))) void*)(g + (size_t)r * 1024 + c8 * 8),
            (__attribute__((address_space(3))) void*)(l + (size_t)t2 * 8), 16, 0, 0);
    }
}

__device__ inline bf16x8 ldsw(const unsigned short* h, int r, int c8)
{
    int slot = r * 8 + (c8 ^ (r & 7));
    return *(const bf16x8*)(h + slot * 8);
}

__global__ __launch_bounds__(512, 2) void kv_gemm8_kernel(
    const unsigned short* __restrict__ A,
    const unsigned short* __restrict__ Bw,
    const float* __restrict__ bias,
    unsigned short* __restrict__ C)
{
    __shared__ unsigned short sh[2][2][2][128 * 64];
    const int mt = blockIdx.x >> 3, nt = blockIdx.x & 7;
    const int t = threadIdx.x;
    const int wid = t >> 6, lane = t & 63;
    const int wm = wid >> 2, wn = wid & 3;
    const int l15 = lane & 15, l16 = lane >> 4;
    const int rB = (wn & 1) * 64;
    const unsigned short* Abase = A + (size_t)mt * 256 * 1024;
    const unsigned short* Bbase = Bw + (size_t)nt * 256 * 1024;

    f32x4 acc[8][4] = {};
    bf16x8 a[4][2], b[4][2];

    stage_half(Abase,                   &sh[0][0][0][0], t);
    stage_half(Abase + 128 * 1024,      &sh[0][0][1][0], t);
    stage_half(Bbase,                   &sh[0][1][0][0], t);
    stage_half(Bbase + 128 * 1024,      &sh[0][1][1][0], t);
    stage_half(Bbase + 64,              &sh[1][1][0][0], t);
    stage_half(Bbase + 128 * 1024 + 64, &sh[1][1][1][0], t);
    asm volatile("s_waitcnt vmcnt(4)" ::: "memory");
    __builtin_amdgcn_s_barrier();

    auto ktile = [&](int T, bool stA, bool stB, bool steady) {
        const int d = T & 1;
        const unsigned short* AH = &sh[d][0][wm][0];
        const unsigned short* BH = &sh[d][1][wn >> 1][0];
        const int kA = (T + 1) * 64;
        const int kB = (T + 2) * 64;

#pragma unroll
        for (int i = 0; i < 4; ++i) {
            a[i][0] = ldsw(AH, i * 16 + l15, l16);
            a[i][1] = ldsw(AH, i * 16 + l15, 4 + l16);
        }
#pragma unroll
        for (int j = 0; j < 2; ++j) {
            b[j][0] = ldsw(BH, rB + j * 16 + l15, l16);
            b[j][1] = ldsw(BH, rB + j * 16 + l15, 4 + l16);
        }
        if (stA) stage_half(Abase + kA, &sh[d ^ 1][0][0][0], t);
        __builtin_amdgcn_sched_barrier(0);
        __builtin_amdgcn_s_barrier();
        asm volatile("s_waitcnt lgkmcnt(0)" ::: "memory");
        __builtin_amdgcn_sched_barrier(0);
        __builtin_amdgcn_s_setprio(1);
#pragma unroll
        for (int i = 0; i < 4; ++i)
#pragma unroll
            for (int j = 0; j < 2; ++j) {
                acc[i][j] = __builtin_amdgcn_mfma_f32_16x16x32_bf16(a[i][0], b[j][0], acc[i][j], 0, 0, 0);
                acc[i][j] = __builtin_amdgcn_mfma_f32_16x16x32_bf16(a[i][1], b[j][1], acc[i][j], 0, 0, 0);
            }
        __builtin_amdgcn_s_setprio(0);
        __builtin_amdgcn_sched_barrier(0);
        __builtin_amdgcn_s_barrier();

#pragma unroll
        for (int j = 2; j < 4; ++j) {
            b[j][0] = ldsw(BH, rB + j * 16 + l15, l16);
            b[j][1] = ldsw(BH, rB + j * 16 + l15, 4 + l16);
        }
        if (stA) stage_half(Abase + 128 * 1024 + kA, &sh[d ^ 1][0][1][0], t);
        __builtin_amdgcn_sched_barrier(0);
        __builtin_amdgcn_s_barrier();
        asm volatile("s_waitcnt lgkmcnt(0)" ::: "memory");
        __builtin_amdgcn_sched_barrier(0);
        __builtin_amdgcn_s_setprio(1);
#pragma unroll
        for (int i = 0; i < 4; ++i)
#pragma unroll
            for (int j = 2; j < 4; ++j) {
                acc[i][j] = __builtin_amdgcn_mfma_f32_16x16x32_bf16(a[i][0], b[j][0], acc[i][j], 0, 0, 0);
                acc[i][j] = __builtin_amdgcn_mfma_f32_16x16x32_bf16(a[i][1], b[j][1], acc[i][j], 0, 0, 0);
            }
        __builtin_amdgcn_s_setprio(0);
        __builtin_amdgcn_sched_barrier(0);
        __builtin_amdgcn_s_barrier();

#pragma unroll
        for (int i = 0; i < 4; ++i) {
            a[i][0] = ldsw(AH, 64 + i * 16 + l15, l16);
            a[i][1] = ldsw(AH, 64 + i * 16 + l15, 4 + l16);
        }
        if (stB) stage_half(Bbase + kB, &sh[d][1][0][0], t);
        __builtin_amdgcn_sched_barrier(0);
        __builtin_amdgcn_s_barrier();
        asm volatile("s_waitcnt lgkmcnt(0)" ::: "memory");
        __builtin_amdgcn_sched_barrier(0);
        __builtin_amdgcn_s_setprio(1);
#pragma unroll
        for (int i = 0; i < 4; ++i)
#pragma unroll
            for (int j = 0; j < 2; ++j) {
                acc[4 + i][j] = __builtin_amdgcn_mfma_f32_16x16x32_bf16(a[i][0], b[j][0], acc[4 + i][j], 0, 0, 0);
                acc[4 + i][j] = __builtin_amdgcn_mfma_f32_16x16x32_bf16(a[i][1], b[j][1], acc[4 + i][j], 0, 0, 0);
            }
        __builtin_amdgcn_s_setprio(0);
        __builtin_amdgcn_sched_barrier(0);
        __builtin_amdgcn_s_barrier();

        if (stB) stage_half(Bbase + 128 * 1024 + kB, &sh[d][1][1][0], t);
        __builtin_amdgcn_sched_barrier(0);
        __builtin_amdgcn_s_barrier();
        asm volatile("s_waitcnt lgkmcnt(0)" ::: "memory");
        __builtin_amdgcn_sched_barrier(0);
        __builtin_amdgcn_s_setprio(1);
#pragma unroll
        for (int i = 0; i < 4; ++i)
#pragma unroll
            for (int j = 2; j < 4; ++j) {
                acc[4 + i][j] = __builtin_amdgcn_mfma_f32_16x16x32_bf16(a[i][0], b[j][0], acc[4 + i][j], 0, 0, 0);
                acc[4 + i][j] = __builtin_amdgcn_mfma_f32_16x16x32_bf16(a[i][1], b[j][1], acc[4 + i][j], 0, 0, 0);
            }
        __builtin_amdgcn_s_setprio(0);
        if (steady) {
            asm volatile("s_waitcnt vmcnt(4)" ::: "memory");
        } else {
            asm volatile("s_waitcnt vmcnt(0)" ::: "memory");
        }
        __builtin_amdgcn_sched_barrier(0);
        __builtin_amdgcn_s_barrier();
    };

    for (int T = 0; T < 14; ++T) ktile(T, true, true, true);
    ktile(14, true, false, false);
    ktile(15, false, false, false);

#pragma unroll
    for (int i = 0; i < 8; ++i) {
        int gmb = mt * 256 + wm * 128 + i * 16 + l16 * 4;
#pragma unroll
        for (int j = 0; j < 4; ++j) {
            int gn = nt * 256 + wn * 64 + j * 16 + l15;
            float bs = bias[gn];
#pragma unroll
            for (int r = 0; r < 4; ++r) {
                int gm = gmb + r;
                if (gm < MROWS) C[(size_t)gm * NKV + gn] = f2b(acc[i][j][r] + bs);
            }
        }
    }
}

// ---------------------------------------------------------------------------
// Kernel 3: attention decode with fused q-projection, one block per (b,h)
// ---------------------------------------------------------------------------
__global__ __launch_bounds__(512) void attn_kernel(
    const unsigned short* __restrict__ normed,
    const unsigned short* __restrict__ Wq, const float* __restrict__ bq,
    const unsigned short* __restrict__ kv, float* __restrict__ o_all)
{
    int b = blockIdx.x >> 4, h = blockIdx.x & 15;
    int t = threadIdx.x;
    int wave = t >> 6, lane = t & 63;
    __shared__ float qs[64];
    __shared__ float sc[LCTX];
    __shared__ float red1[8], red2[8];
    __shared__ float po[8][64];

    {
        const unsigned short* nr = normed + (size_t)(b * LCTX) * DIM;
        bf16x8 n0 = *(const bf16x8*)(nr + lane * 16);
        bf16x8 n1 = *(const bf16x8*)(nr + lane * 16 + 8);
#pragma unroll
        for (int jj = 0; jj < 8; ++jj) {
            int d = wave * 8 + jj;
            const unsigned short* wr = Wq + (size_t)(h * 64 + d) * DIM;
            bf16x8 w0 = *(const bf16x8*)(wr + lane * 16);
            bf16x8 w1 = *(const bf16x8*)(wr + lane * 16 + 8);
            float s = 0.f;
#pragma unroll
            for (int u = 0; u < 8; ++u)
                s += b2f((unsigned short)n0[u]) * b2f((unsigned short)w0[u]);
#pragma unroll
            for (int u = 0; u < 8; ++u)
                s += b2f((unsigned short)n1[u]) * b2f((unsigned short)w1[u]);
#pragma unroll
            for (int o = 32; o > 0; o >>= 1) s += __shfl_down(s, o);
            if (lane == 0) qs[d] = s + bq[h * 64 + d];
        }
    }
    __syncthreads();

    float lmax = -1e30f;
    for (int l = t; l < LCTX; l += 512) {
        const unsigned short* kr = kv + ((size_t)(b * LCTX + l)) * NKV + h * 64;
        const uint4* k4 = (const uint4*)kr;
        float s = 0.f;
#pragma unroll
        for (int c = 0; c < 8; ++c) {
            uint4 u = k4[c];
            s += qs[c * 8 + 0] * b2f((unsigned short)(u.x & 0xffffu));
            s += qs[c * 8 + 1] * b2f((unsigned short)(u.x >> 16));
            s += qs[c * 8 + 2] * b2f((unsigned short)(u.y & 0xffffu));
            s += qs[c * 8 + 3] * b2f((unsigned short)(u.y >> 16));
            s += qs[c * 8 + 4] * b2f((unsigned short)(u.z & 0xffffu));
            s += qs[c * 8 + 5] * b2f((unsigned short)(u.z >> 16));
            s += qs[c * 8 + 6] * b2f((unsigned short)(u.w & 0xffffu));
            s += qs[c * 8 + 7] * b2f((unsigned short)(u.w >> 16));
        }
        s *= 0.125f;
        sc[l] = s;
        lmax = fmaxf(lmax, s);
    }
#pragma unroll
    for (int o = 32; o > 0; o >>= 1) lmax = fmaxf(lmax, __shfl_down(lmax, o));
    if (lane == 0) red1[wave] = lmax;
    __syncthreads();
    float m = red1[0];
#pragma unroll
    for (int w8 = 1; w8 < 8; ++w8) m = fmaxf(m, red1[w8]);

    float lsum = 0.f;
    for (int l = t; l < LCTX; l += 512) {
        float p = __expf(sc[l] - m);
        sc[l] = p;
        lsum += p;
    }
#pragma unroll
    for (int o = 32; o > 0; o >>= 1) lsum += __shfl_down(lsum, o);
    if (lane == 0) red2[wave] = lsum;
    __syncthreads();
    float S = 0.f;
#pragma unroll
    for (int w8 = 0; w8 < 8; ++w8) S += red2[w8];

    int rg = lane >> 3;
    int dc = (lane & 7) * 8;
    float acc[8] = {};
    for (int it = 0; it < 13; ++it) {
        int row = it * 64 + wave * 8 + rg;
        if (row < LCTX) {
            const unsigned short* vr =
                kv + ((size_t)(b * LCTX + row)) * NKV + 1024 + h * 64 + dc;
            bf16x8 v = *(const bf16x8*)vr;
            float p = sc[row];
#pragma unroll
            for (int u = 0; u < 8; ++u) acc[u] += p * b2f((unsigned short)v[u]);
        }
    }
#pragma unroll
    for (int u = 0; u < 8; ++u) {
        acc[u] += __shfl_xor(acc[u], 8);
        acc[u] += __shfl_xor(acc[u], 16);
        acc[u] += __shfl_xor(acc[u], 32);
    }
    if (rg == 0) {
#pragma unroll
        for (int u = 0; u < 8; ++u) po[wave][dc + u] = acc[u];
    }
    __syncthreads();
    if (t < 64) {
        float o = 0.f;
#pragma unroll
        for (int w8 = 0; w8 < 8; ++w8) o += po[w8][t];
        o_all[b * 1024 + h * 64 + t] = o / S;
    }
}

// ---------------------------------------------------------------------------
// Kernel 4: cls_pre[b,i] = ctx0[b,i] + sum_j o_all[b,j]*out_w[i,j] + out_b[i]
// ---------------------------------------------------------------------------
__global__ __launch_bounds__(256) void out_proj_kernel(
    const float* __restrict__ o_all, const float* __restrict__ out_w,
    const float* __restrict__ out_b, const float* __restrict__ ctx0,
    float* __restrict__ cls_pre)
{
    int gw = blockIdx.x * 4 + (threadIdx.x >> 6);
    int lane = threadIdx.x & 63;
    int b = gw >> 10, i = gw & 1023;
    const float* orow = o_all + (size_t)b * 1024;
    const float* wrow = out_w + (size_t)i * 1024;
    float s = 0.f;
#pragma unroll
    for (int kk = 0; kk < 16; ++kk) {
        int k = kk * 64 + lane;
        s += orow[k] * wrow[k];
    }
#pragma unroll
    for (int o = 32; o > 0; o >>= 1) s += __shfl_down(s, o);
    if (lane == 0) cls_pre[gw] = ctx0[gw] + s + out_b[i];
}

// ---------------------------------------------------------------------------
// Kernel 5: LN2 over cls_pre rows; also init outp = cls_pre + b2
// ---------------------------------------------------------------------------
__global__ __launch_bounds__(256) void ln2_kernel(
    const float* __restrict__ cls_pre, const float* __restrict__ g,
    const float* __restrict__ be, const float* __restrict__ b2,
    float* __restrict__ ln2o, float* __restrict__ outp)
{
    int b = blockIdx.x, t = threadIdx.x;
    float4 v = ((const float4*)(cls_pre + (size_t)b * DIM))[t];
    float s = v.x + v.y + v.z + v.w;
    float ss = v.x * v.x + v.y * v.y + v.z * v.z + v.w * v.w;
#pragma unroll
    for (int o = 32; o > 0; o >>= 1) { s += __shfl_down(s, o); ss += __shfl_down(ss, o); }
    __shared__ float rs[4], rss[4];
    int wid = t >> 6, lane = t & 63;
    if (lane == 0) { rs[wid] = s; rss[wid] = ss; }
    __syncthreads();
    float sum = rs[0] + rs[1] + rs[2] + rs[3];
    float sq  = rss[0] + rss[1] + rss[2] + rss[3];
    float mean = sum * (1.0f / DIM);
    float var = sq * (1.0f / DIM) - mean * mean;
    float rstd = rsqrtf(var + 1e-5f);
    float4 gv = ((const float4*)g)[t];
    float4 bv = ((const float4*)be)[t];
    float4 o;
    o.x = (v.x - mean) * rstd * gv.x + bv.x;
    o.y = (v.y - mean) * rstd * gv.y + bv.y;
    o.z = (v.z - mean) * rstd * gv.z + bv.z;
    o.w = (v.w - mean) * rstd * gv.w + bv.w;
    ((float4*)(ln2o + (size_t)b * DIM))[t] = o;
    float4 b2v = ((const float4*)b2)[t];
    float4 oi;
    oi.x = v.x + b2v.x; oi.y = v.y + b2v.y; oi.z = v.z + b2v.z; oi.w = v.w + b2v.w;
    ((float4*)(outp + (size_t)b * DIM))[t] = oi;
}

// ---------------------------------------------------------------------------
// Kernel 6: mlp1 partials
// ---------------------------------------------------------------------------
__global__ __launch_bounds__(256) void mlp1p_kernel(
    const float* __restrict__ ln2v, const float* __restrict__ w1,
    float* __restrict__ part)
{
    __shared__ float l2s[16][256];
    __shared__ float red[4][64][16];
    int jc = blockIdx.x, kq = blockIdx.y;
    int t = threadIdx.x;
#pragma unroll
    for (int b = 0; b < 16; ++b)
        l2s[b][t] = ln2v[(size_t)b * 1024 + kq * 256 + t];
    __syncthreads();
    int jl = t & 63, ks = t >> 6;
    int j = jc * 64 + jl;
    float acc[16] = {};
    for (int kk = 0; kk < 64; ++kk) {
        int kl = ks * 64 + kk;
        float wv = w1[(size_t)(kq * 256 + kl) * 4096 + j];
#pragma unroll
        for (int b = 0; b < 16; ++b) acc[b] += l2s[b][kl] * wv;
    }
#pragma unroll
    for (int b = 0; b < 16; ++b) red[ks][jl][b] = acc[b];
    __syncthreads();
    int jl2 = t & 63, bq = t >> 6;
#pragma unroll
    for (int bb = 0; bb < 4; ++bb) {
        int b = bq * 4 + bb;
        float s = red[0][jl2][b] + red[1][jl2][b] + red[2][jl2][b] + red[3][jl2][b];
        part[((size_t)kq * 16 + b) * 4096 + jc * 64 + jl2] = s;
    }
}

// ---------------------------------------------------------------------------
// Kernel 7: mlp2 with in-LDS reduce+gelu of mlp1 partials, atomicAdd to outp
// ---------------------------------------------------------------------------
__global__ __launch_bounds__(256) void mlp2a_kernel(
    const float* __restrict__ part, const float* __restrict__ b1,
    const float* __restrict__ w2, float* __restrict__ outp)
{
    __shared__ float hseg[16][256];
    __shared__ float red[4][64][16];
    int ic = blockIdx.x, kq = blockIdx.y;
    int t = threadIdx.x;
    {
        int j = kq * 256 + t;
        float bb1 = b1[j];
#pragma unroll
        for (int b = 0; b < 16; ++b) {
            float s = part[((size_t)0 * 16 + b) * 4096 + j]
                    + part[((size_t)1 * 16 + b) * 4096 + j]
                    + part[((size_t)2 * 16 + b) * 4096 + j]
                    + part[((size_t)3 * 16 + b) * 4096 + j];
            s += bb1;
            hseg[b][t] = 0.5f * s * (1.0f + erff(s * 0.70710678118f));
        }
    }
    __syncthreads();
    int il = t & 63, ks = t >> 6;
    int i = ic * 64 + il;
    float acc[16] = {};
    for (int kk = 0; kk < 64; ++kk) {
        int kl = ks * 64 + kk;
        float wv = w2[(size_t)(kq * 256 + kl) * 1024 + i];
#pragma unroll
        for (int b = 0; b < 16; ++b) acc[b] += hseg[b][kl] * wv;
    }
#pragma unroll
    for (int b = 0; b < 16; ++b) red[ks][il][b] = acc[b];
    __syncthreads();
    int il2 = t & 63, bq = t >> 6;
#pragma unroll
    for (int bb = 0; bb < 4; ++bb) {
        int b = bq * 4 + bb;
        float s = red[0][il2][b] + red[1][il2][b] + red[2][il2][b] + red[3][il2][b];
        atomicAdd(&outp[(size_t)b * 1024 + ic * 64 + il2], s);
    }
}

// ---------------------------------------------------------------------------
extern "C" void kernel_launch(void* const* d_in, const int* in_sizes, int n_in,
                              void* d_out, int out_size, void* d_ws, size_t ws_size,
                              hipStream_t stream)
{
    const float* x        = (const float*)d_in[0];
    const float* state    = (const float*)d_in[1];
    const float* acc_ctx  = (const float*)d_in[2];
    const int*   fix_pt   = (const int*)d_in[3];
    const float* in_proj_w = (const float*)d_in[4];
    const float* in_proj_b = (const float*)d_in[5];
    const float* out_w    = (const float*)d_in[6];
    const float* out_b    = (const float*)d_in[7];
    const float* ln1_g    = (const float*)d_in[8];
    const float* ln1_b    = (const float*)d_in[9];
    const float* ln2_g    = (const float*)d_in[10];
    const float* ln2_b    = (const float*)d_in[11];
    const float* w1       = (const float*)d_in[12];
    const float* b1       = (const float*)d_in[13];
    const float* w2       = (const float*)d_in[14];
    const float* b2       = (const float*)d_in[15];
    float* outp = (float*)d_out;

    char* ws = (char*)d_ws;
    unsigned short* normed = (unsigned short*)ws; ws += (size_t)MPAD2 * DIM * 2;
    unsigned short* Wb     = (unsigned short*)ws; ws += (size_t)3072 * DIM * 2;
    unsigned short* kvb    = (unsigned short*)ws; ws += (size_t)MROWS * NKV * 2;
    float* ctx0    = (float*)ws; ws += (size_t)NB * DIM * 4;
    float* o_all   = (float*)ws; ws += (size_t)NB * DIM * 4;
    float* cls_pre = (float*)ws; ws += (size_t)NB * DIM * 4;
    float* ln2v    = (float*)ws; ws += (size_t)NB * DIM * 4;
    float* part    = (float*)ws; ws += (size_t)4 * 16 * 4096 * 4;

    float* newacc = outp + (size_t)NB * DIM;

    hipLaunchKernelGGL(build_ln_kernel, dim3(MPAD2 + 3072), dim3(256), 0, stream,
                       x, state, acc_ctx, fix_pt, ln1_g, ln1_b,
                       in_proj_w, Wb, normed, ctx0, newacc);
    hipLaunchKernelGGL(kv_gemm8_kernel, dim3(392), dim3(512), 0, stream,
                       normed, Wb + (size_t)1024 * DIM, in_proj_b + 1024, kvb);
    hipLaunchKernelGGL(attn_kernel, dim3(256), dim3(512), 0, stream,
                       normed, Wb, in_proj_b, kvb, o_all);
    hipLaunchKernelGGL(out_proj_kernel, dim3(4096), dim3(256), 0, stream,
                       o_all, out_w, out_b, ctx0, cls_pre);
    hipLaunchKernelGGL(ln2_kernel, dim3(16), dim3(256), 0, stream,
                       cls_pre, ln2_g, ln2_b, b2, ln2v, outp);
    hipLaunchKernelGGL(mlp1p_kernel, dim3(64, 4), dim3(256), 0, stream,
                       ln2v, w1, part);
    hipLaunchKernelGGL(mlp2a_kernel, dim3(16, 16), dim3(256), 0, stream,
                       part, b1, w2, outp);
}